// Round 11
// baseline (499.257 us; speedup 1.0000x reference)
//
#include <hip/hip_runtime.h>

// SlotAttention MI355X (gfx950), round 17: R16 + latency pipelining.
// R16 post-mortem: structure works (1 dispatch, 270us steady) but VALUBusy
// 9.8%, HBM 1.2TB/s = latency-bound; each wave held only ~128B in flight.
// Fixes (no structural/numeric change):
//  - light path: 2 groups (8 tiles, 256B/lane) in flight, compute/load overlap
//  - heavy path: prefetch depth 2 (rotating P/Q tile buffers)
//  - gru: next weight chunk prefetched into reg during current stage's dots
// Same: 128 blocks x 1024 thr, block b owns batch b, all block-local.

#define Nn 4096

typedef _Float16 f16;
typedef _Float16 f16x8 __attribute__((ext_vector_type(8)));
typedef _Float16 f16x4 __attribute__((ext_vector_type(4)));
typedef float    f32x4 __attribute__((ext_vector_type(4)));

#define MFMA16(a,b,c) __builtin_amdgcn_mfma_f32_16x16x16f16(a,b,c,0,0,0)
#define MFMA32(a,b,c) __builtin_amdgcn_mfma_f32_16x16x32_f16(a,b,c,0,0,0)
#define LGKM0() asm volatile("s_waitcnt lgkmcnt(0)" ::: "memory")

#if __has_builtin(__builtin_amdgcn_rcpf)
#define RCPF(x) __builtin_amdgcn_rcpf(x)
#else
#define RCPF(x) (1.0f/(x))
#endif

static __device__ __forceinline__ float dot4(f32x4 a, f32x4 b) {
  return a.x*b.x + a.y*b.y + a.z*b.z + a.w*b.w;
}

static __device__ __forceinline__ float dot_row(
    const float (*Wl)[68], int d, const float* v)
{
  float a0 = 0.f, a1 = 0.f;
  #pragma unroll
  for (int jc = 0; jc < 16; jc += 2) {
    a0 += dot4(*(const f32x4*)&Wl[d][jc*4],     *(const f32x4*)(v + jc*4));
    a1 += dot4(*(const f32x4*)&Wl[d][jc*4 + 4], *(const f32x4*)(v + jc*4 + 4));
  }
  return a0 + a1;
}

// commit the prefetched weight chunk into Wl (uniform barriers)
static __device__ __forceinline__ void commit1024(
    float (*Wl)[68], f32x4 wpre, int sr, int sc4)
{
  __syncthreads();                 // protect previous consumers of Wl
  *(f32x4*)&Wl[sr][sc4] = wpre;
  __syncthreads();
}

// in-wave LayerNorm over 64 lanes
static __device__ __forceinline__ float ln64(
    float v, const float* __restrict__ w, const float* __restrict__ bias, int lane)
{
  float s1 = v, s2 = v*v;
  #pragma unroll
  for (int m = 1; m < 64; m <<= 1) {
    s1 += __shfl_xor(s1, m, 64);
    s2 += __shfl_xor(s2, m, 64);
  }
  float mean = s1*(1.f/64.f), var = s2*(1.f/64.f) - mean*mean;
  return (v - mean) * rsqrtf(var + 1e-5f) * w[lane] + bias[lane];
}

static __device__ __forceinline__ void tile_common(
    f16x8 xf0, f16x8 xf1, const f16x8* qkB, float beta,
    f16x8 selLo, f16x8 selHi, bool valid, f32x4* acc, float& csump)
{
  const f32x4 zero4 = {0.f,0.f,0.f,0.f};
  f32x4 lg = zero4;
  lg = MFMA32(xf0, qkB[0], lg);
  lg = MFMA32(xf1, qkB[1], lg);
  float e[4], sm[4];
  #pragma unroll
  for (int j = 0; j < 4; j++) {
    float L = lg[j] + beta;
    e[j] = valid ? __expf(L) : 0.f;
    sm[j] = e[j];
  }
  #pragma unroll
  for (int m = 1; m < 16; m <<= 1)
    #pragma unroll
    for (int j = 0; j < 4; j++) sm[j] += __shfl_xor(sm[j], m, 64);
  f16x4 pp;
  #pragma unroll
  for (int j = 0; j < 4; j++) {
    float p = valid ? (e[j]*RCPF(sm[j]) + 1e-8f) : 0.f;
    csump += p;
    pp[j] = (f16)p;
  }
  #pragma unroll
  for (int nb = 0; nb < 4; nb++) {
    f32x4 tr = MFMA32(nb < 2 ? xf0 : xf1, (nb & 1) ? selHi : selLo, zero4);
    f16x4 xt; xt.x=(f16)tr.x; xt.y=(f16)tr.y; xt.z=(f16)tr.z; xt.w=(f16)tr.w;
    acc[nb] = MFMA16(pp, xt, acc[nb]);
  }
}

// light-path group load/compute (4 tiles per group)
static __device__ __forceinline__ void loadG(
    const f16* __restrict__ xh, size_t tok0, int c, int q, int g,
    f16x8* D0, f16x8* D1)
{
  #pragma unroll
  for (int tt = 0; tt < 4; tt++) {
    const f16* base = xh + (tok0 + (size_t)(g*4 + tt)*16 + c)*64;
    D0[tt] = *(const f16x8*)(base + q*8);
    D1[tt] = *(const f16x8*)(base + 32 + q*8);
  }
}
static __device__ __forceinline__ void compG(
    const f16x8* D0, const f16x8* D1, const f16x8* qkB, float beta,
    f16x8 selLo, f16x8 selHi, bool valid, f32x4* acc, float& csump)
{
  #pragma unroll
  for (int tt = 0; tt < 4; tt++)
    tile_common(D0[tt], D1[tt], qkB, beta, selLo, selHi, valid, acc, csump);
}

__global__ __launch_bounds__(1024) void k_all(
    const float* __restrict__ x_in, const float* __restrict__ noise,
    const float* __restrict__ lnw_in, const float* __restrict__ lnb_in,
    const float* __restrict__ lns_w, const float* __restrict__ lns_b,
    const float* __restrict__ lnm_w, const float* __restrict__ lnm_b,
    const float* __restrict__ mu, const float* __restrict__ ls,
    const float* __restrict__ Wq, const float* __restrict__ Wk,
    const float* __restrict__ Wv,
    const float* __restrict__ W_ih, const float* __restrict__ W_hh,
    const float* __restrict__ b_ih, const float* __restrict__ b_hh,
    const float* __restrict__ W1, const float* __restrict__ b1,
    const float* __restrict__ W2, const float* __restrict__ b2,
    float* __restrict__ slots_out, f16* __restrict__ xh)
{
  __shared__ __align__(16) float Wl[64][68];      // staging
  __shared__ __align__(16) float Mt_l[64][68];    // resident Mt
  __shared__ __align__(16) float accb[16][8][64]; // attn partials
  __shared__ float ldsc[16][8];
  __shared__ float alphas[8];
  __shared__ __align__(16) f16 qkw_l[16][72];
  __shared__ float beta_l[16];
  __shared__ __align__(16) float updv[7][64];
  __shared__ __align__(16) float u2v [7][64];
  __shared__ __align__(16) float prevv[7][64];
  __shared__ __align__(16) float mlnv[7][64];
  __shared__ __align__(16) float sn2 [7][64];
  __shared__ __align__(16) float hbuf[7][128];    // total ~85 KB

  const int b = blockIdx.x, tid = threadIdx.x;
  const int wv = tid >> 6, lane = tid & 63;
  const int q = lane >> 4, c = lane & 15;
  const int sr = tid >> 4, sc4 = (tid & 15) * 4;

  // ---- Mt = 0.125 * Wk^T Wq into resident Mt_l ----
  *(f32x4*)&Wl[sr][sc4]   = *(const f32x4*)(Wk + sr*64 + sc4);
  *(f32x4*)&Mt_l[sr][sc4] = *(const f32x4*)(Wq + sr*64 + sc4);
  for (int i = tid; i < 16*72; i += 1024) ((f16*)qkw_l)[i] = (f16)0.f;
  if (tid >= 7 && tid < 16) beta_l[tid] = 0.f;
  __syncthreads();
  float mtv[4];
  {
    #pragma unroll
    for (int j = 0; j < 4; j++) mtv[j] = 0.f;
    for (int dd = 0; dd < 64; dd++) {
      float wk = Wl[dd][sr];
      const float* wq = &Mt_l[dd][sc4];
      #pragma unroll
      for (int j = 0; j < 4; j++) mtv[j] += wk * wq[j];
    }
  }
  __syncthreads();
  #pragma unroll
  for (int j = 0; j < 4; j++) Mt_l[sr][sc4 + j] = mtv[j] * 0.125f;

  // ---- slots init (waves 0..6 own rows) ----
  float prev = 0.f;
  if (wv < 7)
    prev = mu[lane] + __expf(ls[lane]) * noise[(size_t)(b*7 + wv)*64 + lane];
  __syncthreads();                  // Mt_l ready

  // ---- q0 ----
  if (wv < 7) {
    float sv = ln64(prev, lns_w, lns_b, lane);
    sn2[wv][lane] = sv;
    LGKM0();
    float qk = dot_row(Mt_l, lane, sn2[wv]);
    float qw = qk * lnw_in[lane];
    float bb = qk * lnb_in[lane];
    #pragma unroll
    for (int m = 1; m < 64; m <<= 1) bb += __shfl_xor(bb, m, 64);
    qkw_l[wv][lane] = (f16)qw;
    if (lane == 0) beta_l[wv] = bb;
  }
  __syncthreads();

  f16x8 selLo, selHi;
  #pragma unroll
  for (int j = 0; j < 8; j++) {
    selLo[j] = (f16)((( c>>3)    == q && (c&7) == j) ? 1.0f : 0.0f);
    selHi[j] = (f16)(((c>>3) + 2 == q && (c&7) == j) ? 1.0f : 0.0f);
  }
  const bool valid = (c < 7);
  const f32x4 zero4 = {0.f,0.f,0.f,0.f};

  for (int it = 0; it < 3; ++it) {
    // ================= attn: wave wv = tokens [wv*256,(wv+1)*256) ==========
    f16x8 qkB[2];
    qkB[0] = *(const f16x8*)&qkw_l[c][q*8];
    qkB[1] = *(const f16x8*)&qkw_l[c][32 + q*8];
    const float beta = beta_l[c];

    f32x4 acc[4] = {zero4, zero4, zero4, zero4};
    float csump = 0.f;
    const size_t tok0 = (size_t)b*Nn + (size_t)wv*256;

    if (it == 0) {
      // heavy: fp32 x -> LN -> fp16 xn store + tile math; prefetch depth 2
      f32x4 P[4], Q[4];
      {
        const float* b0 = x_in + (tok0 + c)*64;
        P[0] = *(const f32x4*)(b0 + q*8);
        P[1] = *(const f32x4*)(b0 + q*8 + 4);
        P[2] = *(const f32x4*)(b0 + 32 + q*8);
        P[3] = *(const f32x4*)(b0 + 32 + q*8 + 4);
        const float* b1_ = x_in + (tok0 + 16 + c)*64;
        Q[0] = *(const f32x4*)(b1_ + q*8);
        Q[1] = *(const f32x4*)(b1_ + q*8 + 4);
        Q[2] = *(const f32x4*)(b1_ + 32 + q*8);
        Q[3] = *(const f32x4*)(b1_ + 32 + q*8 + 4);
      }
      #pragma unroll
      for (int t = 0; t < 16; t++) {
        f32x4 xv[4];
        #pragma unroll
        for (int i = 0; i < 4; i++) xv[i] = (t & 1) ? Q[i] : P[i];
        if (t < 14) {
          const float* base = x_in + (tok0 + (size_t)(t+2)*16 + c)*64;
          if (t & 1) {
            Q[0] = *(const f32x4*)(base + q*8);
            Q[1] = *(const f32x4*)(base + q*8 + 4);
            Q[2] = *(const f32x4*)(base + 32 + q*8);
            Q[3] = *(const f32x4*)(base + 32 + q*8 + 4);
          } else {
            P[0] = *(const f32x4*)(base + q*8);
            P[1] = *(const f32x4*)(base + q*8 + 4);
            P[2] = *(const f32x4*)(base + 32 + q*8);
            P[3] = *(const f32x4*)(base + 32 + q*8 + 4);
          }
        }
        float sx  = (xv[0].x+xv[0].y+xv[0].z+xv[0].w) + (xv[1].x+xv[1].y+xv[1].z+xv[1].w)
                  + (xv[2].x+xv[2].y+xv[2].z+xv[2].w) + (xv[3].x+xv[3].y+xv[3].z+xv[3].w);
        float sxx = dot4(xv[0],xv[0]) + dot4(xv[1],xv[1])
                  + dot4(xv[2],xv[2]) + dot4(xv[3],xv[3]);
        sx  += __shfl_xor(sx, 16, 64);  sx  += __shfl_xor(sx, 32, 64);
        sxx += __shfl_xor(sxx, 16, 64); sxx += __shfl_xor(sxx, 32, 64);
        float mean = sx*(1.f/64.f);
        float rstd = rsqrtf(sxx*(1.f/64.f) - mean*mean + 1e-5f);
        float mr2 = mean * rstd;
        f16x8 xf0, xf1;
        #pragma unroll
        for (int j = 0; j < 4; j++) {
          xf0[j]   = (f16)(xv[0][j]*rstd - mr2);
          xf0[4+j] = (f16)(xv[1][j]*rstd - mr2);
          xf1[j]   = (f16)(xv[2][j]*rstd - mr2);
          xf1[4+j] = (f16)(xv[3][j]*rstd - mr2);
        }
        f16* xo = xh + (tok0 + (size_t)t*16 + c)*64;
        *(f16x8*)(xo + q*8)      = xf0;
        *(f16x8*)(xo + 32 + q*8) = xf1;
        tile_common(xf0, xf1, qkB, beta, selLo, selHi, valid, acc, csump);
      }
    } else {
      // light: 2 groups (8 tiles, 256B/lane) in flight
      f16x8 A0[4], A1[4], B0[4], B1[4];
      loadG(xh, tok0, c, q, 0, A0, A1);
      loadG(xh, tok0, c, q, 1, B0, B1);
      compG(A0, A1, qkB, beta, selLo, selHi, valid, acc, csump);
      loadG(xh, tok0, c, q, 2, A0, A1);
      compG(B0, B1, qkB, beta, selLo, selHi, valid, acc, csump);
      loadG(xh, tok0, c, q, 3, B0, B1);
      compG(A0, A1, qkB, beta, selLo, selHi, valid, acc, csump);
      compG(B0, B1, qkB, beta, selLo, selHi, valid, acc, csump);
    }

    csump += __shfl_xor(csump, 16, 64); csump += __shfl_xor(csump, 32, 64);
    if (q == 0 && c < 7) ldsc[wv][c] = csump;
    if (q < 2) {
      #pragma unroll
      for (int nb = 0; nb < 4; nb++)
        #pragma unroll
        for (int rr = 0; rr < 4; rr++)
          accb[wv][q*4 + rr][nb*16 + c] = acc[nb][rr];
    }
    if (wv < 7) prevv[wv][lane] = prev;
    __syncthreads();

    // prefetch first gru chunk while reducing
    f32x4 wpre = *(const f32x4*)(Wv + (size_t)sr*64 + sc4);

    // ---- in-block reduction over 16 waves ----
    if (tid < 7) {
      float a = 0.f;
      #pragma unroll
      for (int w2 = 0; w2 < 16; w2++) a += ldsc[w2][tid];
      alphas[tid] = a;
    }
    __syncthreads();
    if (tid < 448) {
      int row = tid >> 6, d = tid & 63;
      float Y = 0.f;
      #pragma unroll
      for (int w2 = 0; w2 < 16; w2++) Y += accb[w2][row][d];
      updv[row][d] = lnw_in[d]*(Y / alphas[row]) + lnb_in[d];
    }

    // ================= gru: commit chunk i, prefetch i+1, compute ==========
    commit1024(Wl, wpre, sr, sc4);                               // Wv
    wpre = *(const f32x4*)(W_ih + (size_t)sr*64 + sc4);
    if (wv < 7) u2v[wv][lane] = dot_row(Wl, lane, updv[wv]);

    commit1024(Wl, wpre, sr, sc4);                               // W_ih r
    wpre = *(const f32x4*)(W_ih + 4096 + (size_t)sr*64 + sc4);
    float air = 0.f, aiz = 0.f, ain = 0.f, ahr = 0.f, ahz = 0.f, ahn = 0.f;
    if (wv < 7) air = b_ih[lane]     + dot_row(Wl, lane, u2v[wv]);

    commit1024(Wl, wpre, sr, sc4);                               // W_ih z
    wpre = *(const f32x4*)(W_ih + 8192 + (size_t)sr*64 + sc4);
    if (wv < 7) aiz = b_ih[64+lane]  + dot_row(Wl, lane, u2v[wv]);

    commit1024(Wl, wpre, sr, sc4);                               // W_ih n
    wpre = *(const f32x4*)(W_hh + (size_t)sr*64 + sc4);
    if (wv < 7) ain = b_ih[128+lane] + dot_row(Wl, lane, u2v[wv]);

    commit1024(Wl, wpre, sr, sc4);                               // W_hh r
    wpre = *(const f32x4*)(W_hh + 4096 + (size_t)sr*64 + sc4);
    if (wv < 7) ahr = b_hh[lane]     + dot_row(Wl, lane, prevv[wv]);

    commit1024(Wl, wpre, sr, sc4);                               // W_hh z
    wpre = *(const f32x4*)(W_hh + 8192 + (size_t)sr*64 + sc4);
    if (wv < 7) ahz = b_hh[64+lane]  + dot_row(Wl, lane, prevv[wv]);

    commit1024(Wl, wpre, sr, sc4);                               // W_hh n
    wpre = *(const f32x4*)(W1 + (size_t)sr*64 + sc4);
    if (wv < 7) ahn = b_hh[128+lane] + dot_row(Wl, lane, prevv[wv]);

    float hnew = 0.f;
    if (wv < 7) {
      float rg = 1.f/(1.f + __expf(-(air+ahr)));
      float zg = 1.f/(1.f + __expf(-(aiz+ahz)));
      float ng = tanhf(ain + rg*ahn);
      hnew = (1.f - zg)*ng + zg*prev;
      mlnv[wv][lane] = ln64(hnew, lnm_w, lnm_b, lane);
    }

    commit1024(Wl, wpre, sr, sc4);                               // W1 a
    wpre = *(const f32x4*)(W1 + 4096 + (size_t)sr*64 + sc4);
    float h0 = 0.f, h1 = 0.f;
    if (wv < 7) h0 = fmaxf(b1[lane]    + dot_row(Wl, lane, mlnv[wv]), 0.f);

    commit1024(Wl, wpre, sr, sc4);                               // W1 b
    wpre = *(const f32x4*)(W2 + (size_t)sr*128 + sc4);
    if (wv < 7) {
      h1 = fmaxf(b1[64+lane] + dot_row(Wl, lane, mlnv[wv]), 0.f);
      hbuf[wv][lane] = h0; hbuf[wv][64+lane] = h1;
    }

    commit1024(Wl, wpre, sr, sc4);                               // W2 a
    wpre = *(const f32x4*)(W2 + 64 + (size_t)sr*128 + sc4);
    float out = 0.f;
    if (wv < 7) out = hnew + b2[lane] + dot_row(Wl, lane, hbuf[wv]);

    commit1024(Wl, wpre, sr, sc4);                               // W2 b
    if (wv < 7) {
      out += dot_row(Wl, lane, hbuf[wv] + 64);
      prev = out;
    }

    if (it == 2) {
      if (wv < 7) slots_out[(size_t)(b*7 + wv)*64 + lane] = out;
    } else {
      if (wv < 7) {
        float sv = ln64(out, lns_w, lns_b, lane);
        sn2[wv][lane] = sv;
        LGKM0();
        float qk = dot_row(Mt_l, lane, sn2[wv]);
        float qw = qk * lnw_in[lane];
        float bb = qk * lnb_in[lane];
        #pragma unroll
        for (int m = 1; m < 64; m <<= 1) bb += __shfl_xor(bb, m, 64);
        qkw_l[wv][lane] = (f16)qw;
        if (lane == 0) beta_l[wv] = bb;
      }
      __syncthreads();              // q visible to all waves for next attn
    }
  }
}

// ----------------------------------------------------------- kernel_launch --
extern "C" void kernel_launch(void* const* d_in, const int* in_sizes, int n_in,
                              void* d_out, int out_size, void* d_ws, size_t ws_size,
                              hipStream_t stream) {
  const float* inputs  = (const float*)d_in[0];
  const float* noise   = (const float*)d_in[1];
  const float* ln_in_w = (const float*)d_in[2];
  const float* ln_in_b = (const float*)d_in[3];
  const float* ln_sl_w = (const float*)d_in[4];
  const float* ln_sl_b = (const float*)d_in[5];
  const float* ln_ml_w = (const float*)d_in[6];
  const float* ln_ml_b = (const float*)d_in[7];
  const float* mu   = (const float*)d_in[8];
  const float* ls   = (const float*)d_in[9];
  const float* Wq   = (const float*)d_in[10];
  const float* Wk   = (const float*)d_in[11];
  const float* Wv   = (const float*)d_in[12];
  const float* W_ih = (const float*)d_in[13];
  const float* W_hh = (const float*)d_in[14];
  const float* b_ih = (const float*)d_in[15];
  const float* b_hh = (const float*)d_in[16];
  const float* W1 = (const float*)d_in[17];
  const float* b1 = (const float*)d_in[18];
  const float* W2 = (const float*)d_in[19];
  const float* b2 = (const float*)d_in[20];

  float* slots = (float*)d_out;

  // workspace: xh f16 [128][4096][64] only
  const size_t NEED = 67108864;
  if (ws_size < NEED) return;
  f16* xh = (f16*)d_ws;

  k_all<<<128, 1024, 0, stream>>>(
      inputs, noise, ln_in_w, ln_in_b, ln_sl_w, ln_sl_b, ln_ml_w, ln_ml_b,
      mu, ls, Wq, Wk, Wv, W_ih, W_hh, b_ih, b_hh, W1, b1, W2, b2,
      slots, xh);
}